// Round 14
// baseline (40.861 us; speedup 1.0000x reference)
//
#include <hip/hip_runtime.h>
#include <math.h>

// B=16, N=128, h=256, goal_dim=64, obs_dim=128, local=64, skills=16
// R14: Wo folded into V INSIDE proj (chained GEMM: V16 = agents*Wv^T + bv,
// VWO16 = V16*Wo^T), single-bf16 VWOT. Two launches. attn has no out-proj.

typedef float f32x4 __attribute__((ext_vector_type(4)));
typedef short s16x8 __attribute__((ext_vector_type(8)));

// ---- workspace layout (float offsets) ----
#define QBF_OFF   0        // bf16 [2048][256]            262144 floats
#define KBF_OFF   262144   // bf16 [2048][256]            262144 floats
#define VWOT_OFF  524288   // bf16 [16][256 g][128 m]     262144 floats

// ---- output layout (float offsets, tuple return order) ----
#define LOGIT_OFF 0        // [16][128][16]
#define MASK_OFF  32768    // [16][128][128]
#define ATTN_OFF  294912   // [16][128][128]
#define OUT_OFF   557056   // [16][128][256]

static __device__ __forceinline__ unsigned short f2bf(float x) {
  unsigned int u = __float_as_uint(x);
  u = (u + 0x7fffu + ((u >> 16) & 1u)) >> 16;   // RNE
  return (unsigned short)u;
}
static __device__ __forceinline__ float bf2f(unsigned short h) {
  return __uint_as_float(((unsigned int)h) << 16);
}
static __device__ __forceinline__ void split8(const float* __restrict__ p,
                                              s16x8* hi, s16x8* lo) {
  float4 x0 = *(const float4*)p;
  float4 x1 = *(const float4*)(p + 4);
  float xs[8] = {x0.x, x0.y, x0.z, x0.w, x1.x, x1.y, x1.z, x1.w};
#pragma unroll
  for (int j = 0; j < 8; j++) {
    unsigned short h = f2bf(xs[j]);
    (*hi)[j] = (short)h;
    (*lo)[j] = (short)f2bf(xs[j] - bf2f(h));
  }
}
static __device__ __forceinline__ unsigned int cvtpk(float a, float b) {
  unsigned int d;
  asm("v_cvt_pk_bf16_f32 %0, %1, %2" : "=v"(d) : "v"(a), "v"(b));
  return d;
}
// single-bf16 fragment from 8 consecutive f32
static __device__ __forceinline__ s16x8 g2f8(const float* __restrict__ p) {
  float4 x = *(const float4*)p;
  float4 y = *(const float4*)(p + 4);
  union { unsigned int u[4]; s16x8 v; } r;
  r.u[0] = cvtpk(x.x, x.y); r.u[1] = cvtpk(x.z, x.w);
  r.u[2] = cvtpk(y.x, y.y); r.u[3] = cvtpk(y.z, y.w);
  return r.v;
}
#define MFMA(a, b, c) __builtin_amdgcn_mfma_f32_16x16x32_bf16((a), (b), (c), 0, 0, 0)

// ---------------- projv_k: 128 blocks x 1024 threads ----------------
// block = (batch = 2*(bid&7) + ((bid>>3)&1), 16-row window rw = bid>>4).
// Q,K (hi/lo); V (hi/lo) -> LDS bf16; VWO = V16 x Wo^T (single bf16) -> VWOT.
__global__ __launch_bounds__(1024) void projv_k(
    const float* __restrict__ goals, const float* __restrict__ agents,
    const float* __restrict__ Wq, const float* __restrict__ bq,
    const float* __restrict__ Wk, const float* __restrict__ bk,
    const float* __restrict__ Wv, const float* __restrict__ bv,
    const float* __restrict__ Wo, float* __restrict__ ws) {
  unsigned short* qbf  = (unsigned short*)(ws + QBF_OFF);
  unsigned short* kbf  = (unsigned short*)(ws + KBF_OFF);
  unsigned short* vwot = (unsigned short*)(ws + VWOT_OFF);

  __shared__ __align__(16) float xg[16 * 68];
  __shared__ __align__(16) float xa[16 * 132];
  __shared__ __align__(16) unsigned short vbuf[16 * 264];

  int t = threadIdx.x;
  int bid = blockIdx.x;
  int xcd = bid & 7, j = bid >> 3;
  int batch = 2 * xcd + (j & 1);
  int rw = j >> 1;                       // 0..7
  int r0 = batch * 128 + rw * 16;
  int m0 = rw * 16;

  xg[(t >> 6) * 68 + (t & 63)] = goals[(size_t)r0 * 64 + (t & 1023)];
  {
    int i = t;
    xa[(i >> 7) * 132 + (i & 127)] = agents[(size_t)r0 * 128 + i];
    i = t + 1024;
    xa[(i >> 7) * 132 + (i & 127)] = agents[(size_t)r0 * 128 + i];
  }
  __syncthreads();

  int w = t >> 6, l = t & 63, lr = l & 15, lc = l >> 4;
  int oc = w * 16 + lr;                  // 0..255

  // ---- Q: k=64, hi/lo ----
  {
    f32x4 acc = {0.f, 0.f, 0.f, 0.f};
#pragma unroll
    for (int kk = 0; kk < 2; kk++) {
      s16x8 ahi, alo, bhi, blo;
      split8(&xg[lr * 68 + kk * 32 + lc * 8], &ahi, &alo);
      split8(&Wq[(size_t)oc * 64 + kk * 32 + lc * 8], &bhi, &blo);
      acc = MFMA(ahi, bhi, acc);
      acc = MFMA(alo, bhi, acc);
      acc = MFMA(ahi, blo, acc);
    }
    float bqv = bq[oc];
#pragma unroll
    for (int q = 0; q < 4; q++)
      qbf[(size_t)(r0 + 4 * lc + q) * 256 + oc] = f2bf(acc[q] + bqv);
  }
  // ---- K: k=128, hi/lo ----
  {
    f32x4 acc = {0.f, 0.f, 0.f, 0.f};
#pragma unroll
    for (int kk = 0; kk < 4; kk++) {
      s16x8 ahi, alo, bhi, blo;
      split8(&xa[lr * 132 + kk * 32 + lc * 8], &ahi, &alo);
      split8(&Wk[(size_t)oc * 128 + kk * 32 + lc * 8], &bhi, &blo);
      acc = MFMA(ahi, bhi, acc);
      acc = MFMA(alo, bhi, acc);
      acc = MFMA(ahi, blo, acc);
    }
    float bkv = bk[oc];
#pragma unroll
    for (int q = 0; q < 4; q++)
      kbf[(size_t)(r0 + 4 * lc + q) * 256 + oc] = f2bf(acc[q] + bkv);
  }
  // ---- V: k=128, hi/lo, +bv -> LDS bf16 ----
  {
    f32x4 acc = {0.f, 0.f, 0.f, 0.f};
#pragma unroll
    for (int kk = 0; kk < 4; kk++) {
      s16x8 ahi, alo, bhi, blo;
      split8(&xa[lr * 132 + kk * 32 + lc * 8], &ahi, &alo);
      split8(&Wv[(size_t)oc * 128 + kk * 32 + lc * 8], &bhi, &blo);
      acc = MFMA(ahi, bhi, acc);
      acc = MFMA(alo, bhi, acc);
      acc = MFMA(ahi, blo, acc);
    }
    float bvv = bv[oc];
#pragma unroll
    for (int q = 0; q < 4; q++)
      vbuf[(4 * lc + q) * 264 + oc] = f2bf(acc[q] + bvv);
  }
  __syncthreads();

  // ---- VWO = V16 x Wo^T (single bf16, k=256) -> VWOT[b][g][m] ----
  {
    f32x4 acc = {0.f, 0.f, 0.f, 0.f};
#pragma unroll
    for (int kk = 0; kk < 8; kk++) {
      s16x8 a = *(const s16x8*)(vbuf + lr * 264 + kk * 32 + lc * 8);
      acc = MFMA(a, g2f8(&Wo[(size_t)oc * 256 + kk * 32 + lc * 8]), acc);
    }
#pragma unroll
    for (int q = 0; q < 4; q++)
      vwot[(size_t)(batch * 256 + oc) * 128 + m0 + 4 * lc + q] = f2bf(acc[q]);
  }
}

// ---------------- attn_k: 256 blocks x 1024 thr, phases L,S,PVW,SK ----------
__global__ __launch_bounds__(1024) void attn_k(
    const float* __restrict__ goals, const float* __restrict__ agents_local,
    const float* __restrict__ u1, const float* __restrict__ u2,
    const float* __restrict__ bo, const float* __restrict__ Wsm,
    const float* __restrict__ bs, const float* __restrict__ ws,
    float* __restrict__ out) {
  const unsigned short* Qbf  = (const unsigned short*)(ws + QBF_OFF);
  const unsigned short* Kbf  = (const unsigned short*)(ws + KBF_OFF);
  const unsigned short* VWOT = (const unsigned short*)(ws + VWOT_OFF);
  float* o_logit = out + LOGIT_OFF;
  float* o_mask  = out + MASK_OFF;
  float* o_attn  = out + ATTN_OFF;
  float* o_out   = out + OUT_OFF;

  int bid = blockIdx.x;
  int xcd = bid & 7, idx = bid >> 3;
  int b  = 2 * xcd + (idx & 1);
  int n0 = (idx >> 1) << 3;
  int rtile = n0 & 0x70;
  int soff  = n0 & 8;
  int t = threadIdx.x;
  int w = t >> 6, l = t & 63, lr = l & 15, lc = l >> 4;

  __shared__ __align__(16) float Spp[2][8][132];
  __shared__ __align__(16) unsigned short Wb[16 * 136];
  __shared__ __align__(16) float outb[8 * 260];
  __shared__ float redmax[8][2], redsum[8][2];

  // ---- prefetch: u1/u2 (nontemporal), bo, 4 VWOT B-frags ----
  int pm = t & 127, prl = t >> 7;
  int prow = b * 128 + n0 + prl;
  float uu1 = __builtin_nontemporal_load(&u1[(size_t)prow * 128 + pm]);
  float uu2 = __builtin_nontemporal_load(&u2[(size_t)prow * 128 + pm]);
  int g0 = w * 16;
  float bov = bo[g0 + lr];
  const s16x8* vhp = (const s16x8*)(VWOT + (size_t)(b * 256 + g0 + lr) * 128);
  s16x8 fh0 = vhp[lc], fh1 = vhp[4 + lc], fh2 = vhp[8 + lc], fh3 = vhp[12 + lc];

  // ---- phase L: logits MFMA. wave w: m-tile = w&7, k-half = w>>3 ----
  {
    int mt = w & 7, kh = w >> 3;
    const s16x8* ap = (const s16x8*)(Qbf + (size_t)(b * 128 + rtile + lr) * 256 + kh * 128);
    const s16x8* bp = (const s16x8*)(Kbf + (size_t)(b * 128 + mt * 16 + lr) * 256 + kh * 128);
    f32x4 acc = {0.f, 0.f, 0.f, 0.f};
#pragma unroll
    for (int kk = 0; kk < 4; kk++)
      acc = MFMA(ap[kk * 4 + lc], bp[kk * 4 + lc], acc);
    if ((lc >> 1) == (soff >> 3)) {
#pragma unroll
      for (int q = 0; q < 4; q++) Spp[kh][(4 * lc + q) & 7][mt * 16 + lr] = acc[q];
    }
    if (t < 544) ((unsigned int*)(Wb + (soff ^ 8) * 136))[t] = 0u;
  }
  __syncthreads();

  // ---- phase S: gumbel-sigmoid mask + scores + softmax ----
  {
    int half = (t >> 6) & 1;
    float lg = (Spp[0][prl][pm] + Spp[1][prl][pm]) * 0.0625f;
    float g1 = -__logf(-__logf(uu1 + 1e-20f) + 1e-20f);
    float g2 = -__logf(-__logf(uu2 + 1e-20f) + 1e-20f);
    float mkv = 1.0f / (1.0f + __expf(-(lg + g1 - g2)));   // TAU = 1
    __builtin_nontemporal_store(mkv, &o_mask[(size_t)prow * 128 + pm]);
    float sc = lg + __logf(mkv + 1e-8f);
    float v = sc;
#pragma unroll
    for (int off = 32; off >= 1; off >>= 1) v = fmaxf(v, __shfl_xor(v, off));
    if (l == 0) redmax[prl][half] = v;
    __syncthreads();
    float rmax = fmaxf(redmax[prl][0], redmax[prl][1]);
    float e = __expf(sc - rmax);
    float s = e;
#pragma unroll
    for (int off = 32; off >= 1; off >>= 1) s += __shfl_xor(s, off);
    if (l == 0) redsum[prl][half] = s;
    __syncthreads();
    float rsum = redsum[prl][0] + redsum[prl][1];
    float attn = e / rsum;
    __builtin_nontemporal_store(attn, &o_attn[(size_t)prow * 128 + pm]);
    Wb[(soff + prl) * 136 + pm] = f2bf(attn * mkv);
  }
  __syncthreads();

  // ---- phase PVW: out = Wb x VWO + bo. wave w -> g-tile g0 (4 MFMAs) ----
  {
    s16x8 a0 = *(const s16x8*)(Wb + lr * 136 + 0 * 32 + lc * 8);
    s16x8 a1 = *(const s16x8*)(Wb + lr * 136 + 1 * 32 + lc * 8);
    s16x8 a2 = *(const s16x8*)(Wb + lr * 136 + 2 * 32 + lc * 8);
    s16x8 a3 = *(const s16x8*)(Wb + lr * 136 + 3 * 32 + lc * 8);
    f32x4 acc = {0.f, 0.f, 0.f, 0.f};
    acc = MFMA(a0, fh0, acc);
    acc = MFMA(a1, fh1, acc);
    acc = MFMA(a2, fh2, acc);
    acc = MFMA(a3, fh3, acc);
    if ((lc >> 1) == (soff >> 3)) {
#pragma unroll
      for (int q = 0; q < 4; q++) {
        int rloc = (4 * lc + q) & 7;
        float val = acc[q] + bov;
        __builtin_nontemporal_store(val, &o_out[(size_t)(b * 128 + n0 + rloc) * 256 + g0 + lr]);
        outb[rloc * 260 + g0 + lr] = val;
      }
    }
  }
  __syncthreads();

  // ---- phase SK: skill logits. t = (rloc<<7)|(s<<3)|p, 8-way split-K ----
  {
    int rloc = t >> 7, s = (t >> 3) & 15, p = t & 7;
    int row = b * 128 + n0 + rloc;
    const float4* Ws4 = (const float4*)(Wsm + s * 384);
    const float4* lp4 = (const float4*)(agents_local + (size_t)row * 64);
    const float4* gp4 = (const float4*)(goals + (size_t)row * 64);
    float acc = 0.f;
#pragma unroll
    for (int i = 0; i < 12; i++) {
      int cc = p * 48 + i * 4;
      float4 c4;
      if (cc < 64)       c4 = lp4[cc >> 2];
      else if (cc < 128) c4 = gp4[(cc - 64) >> 2];
      else               c4 = *(const float4*)&outb[rloc * 260 + (cc - 128)];
      float4 w4 = Ws4[cc >> 2];
      acc = fmaf(w4.x, c4.x, fmaf(w4.y, c4.y, fmaf(w4.z, c4.z, fmaf(w4.w, c4.w, acc))));
    }
    acc += __shfl_xor(acc, 1);
    acc += __shfl_xor(acc, 2);
    acc += __shfl_xor(acc, 4);
    if (p == 0) __builtin_nontemporal_store(acc + bs[s], &o_logit[row * 16 + s]);
  }
}

extern "C" void kernel_launch(void* const* d_in, const int* in_sizes, int n_in,
                              void* d_out, int out_size, void* d_ws, size_t ws_size,
                              hipStream_t stream) {
  const float* goals        = (const float*)d_in[0];
  const float* agents       = (const float*)d_in[1];
  const float* agents_local = (const float*)d_in[2];
  const float* u1           = (const float*)d_in[3];
  const float* u2           = (const float*)d_in[4];
  const float* Wq = (const float*)d_in[5];
  const float* bq = (const float*)d_in[6];
  const float* Wk = (const float*)d_in[7];
  const float* bk = (const float*)d_in[8];
  const float* Wv = (const float*)d_in[9];
  const float* bv = (const float*)d_in[10];
  const float* Wo = (const float*)d_in[11];
  const float* bo = (const float*)d_in[12];
  const float* Wsm = (const float*)d_in[13];
  const float* bs  = (const float*)d_in[14];
  float* out = (float*)d_out;
  float* ws  = (float*)d_ws;

  projv_k<<<128, 1024, 0, stream>>>(goals, agents, Wq, bq, Wk, bk, Wv, bv, Wo, ws);
  attn_k<<<256, 1024, 0, stream>>>(goals, agents_local, u1, u2, bo, Wsm, bs, ws, out);
}

// Round 15
// 35.056 us; speedup vs baseline: 1.1656x; 1.1656x over previous
//
#include <hip/hip_runtime.h>
#include <math.h>

// B=16, N=128, h=256, goal_dim=64, obs_dim=128, local=64, skills=16
// R15: Wvo fold (Wvo = Wo*Wv, bvo = Wo*bv), all-single-bf16 VWOT path.
// wvo_k: 8 MFMAs, single-bf16. proj_k: R10 structure + VWO phase. attn_k: R14.

typedef float f32x4 __attribute__((ext_vector_type(4)));
typedef short s16x8 __attribute__((ext_vector_type(8)));

// ---- workspace layout (float offsets, non-overlapping) ----
#define WVO_OFF   0        // bf16 [256 g][128 d]          16384 floats
#define BVO       16384    // f32 [256]                      256 floats
#define QBF_OFF   16640    // bf16 [2048][256]            262144 floats
#define KBF_OFF   278784   // bf16 [2048][256]            262144 floats
#define VWOT_OFF  540928   // bf16 [16][256 g][128 m]     262144 floats
// end 803072 floats = 3.2 MB

// ---- output layout (float offsets, tuple return order) ----
#define LOGIT_OFF 0        // [16][128][16]
#define MASK_OFF  32768    // [16][128][128]
#define ATTN_OFF  294912   // [16][128][128]
#define OUT_OFF   557056   // [16][128][256]

static __device__ __forceinline__ unsigned short f2bf(float x) {
  unsigned int u = __float_as_uint(x);
  u = (u + 0x7fffu + ((u >> 16) & 1u)) >> 16;   // RNE
  return (unsigned short)u;
}
static __device__ __forceinline__ float bf2f(unsigned short h) {
  return __uint_as_float(((unsigned int)h) << 16);
}
static __device__ __forceinline__ void split8(const float* __restrict__ p,
                                              s16x8* hi, s16x8* lo) {
  float4 x0 = *(const float4*)p;
  float4 x1 = *(const float4*)(p + 4);
  float xs[8] = {x0.x, x0.y, x0.z, x0.w, x1.x, x1.y, x1.z, x1.w};
#pragma unroll
  for (int j = 0; j < 8; j++) {
    unsigned short h = f2bf(xs[j]);
    (*hi)[j] = (short)h;
    (*lo)[j] = (short)f2bf(xs[j] - bf2f(h));
  }
}
static __device__ __forceinline__ unsigned int cvtpk(float a, float b) {
  unsigned int d;
  asm("v_cvt_pk_bf16_f32 %0, %1, %2" : "=v"(d) : "v"(a), "v"(b));
  return d;
}
static __device__ __forceinline__ s16x8 g2f8(const float* __restrict__ p) {
  float4 x = *(const float4*)p;
  float4 y = *(const float4*)(p + 4);
  union { unsigned int u[4]; s16x8 v; } r;
  r.u[0] = cvtpk(x.x, x.y); r.u[1] = cvtpk(x.z, x.w);
  r.u[2] = cvtpk(y.x, y.y); r.u[3] = cvtpk(y.z, y.w);
  return r.v;
}
#define MFMA(a, b, c) __builtin_amdgcn_mfma_f32_16x16x32_bf16((a), (b), (c), 0, 0, 0)

// ---------------- wvo_k: Wvo = bf16(Wo) x bf16(Wv), bvo = Wo x bv ------------
// 32 blocks x 256 thr. block = (g-tile gt = bid>>1, d-half dh = bid&1).
__global__ __launch_bounds__(256) void wvo_k(
    const float* __restrict__ Wo, const float* __restrict__ Wv,
    const float* __restrict__ bv, float* __restrict__ ws) {
  unsigned short* wvo = (unsigned short*)(ws + WVO_OFF);
  float* bvo = ws + BVO;

  __shared__ float wv_l[256 * 64];   // Wv[:, dh*64 : +64], 64 KB

  int t = threadIdx.x, bid = blockIdx.x;
  int gt = bid >> 1, dh = bid & 1;
  int g0t = gt * 16;

  for (int i = t; i < 16384; i += 256) {
    int h = i >> 6, dl = i & 63;
    wv_l[h * 64 + dl] = Wv[h * 128 + dh * 64 + dl];
  }
  if (dh == 0) {                      // bvo[g0t + gl]
    int gl = t >> 4, p = t & 15;
    const float* wor = Wo + (size_t)(g0t + gl) * 256 + p * 16;
    float bacc = 0.f;
#pragma unroll
    for (int j = 0; j < 16; j++) bacc = fmaf(bv[p * 16 + j], wor[j], bacc);
    bacc += __shfl_xor(bacc, 1);
    bacc += __shfl_xor(bacc, 2);
    bacc += __shfl_xor(bacc, 4);
    bacc += __shfl_xor(bacc, 8);
    if (p == 0) bvo[g0t + gl] = bacc;
  }
  __syncthreads();

  int w = t >> 6, l = t & 63, lr = l & 15, lc = l >> 4;
  int d0 = dh * 64 + w * 16, dl0 = w * 16;
  f32x4 acc = {0.f, 0.f, 0.f, 0.f};
#pragma unroll
  for (int kk = 0; kk < 8; kk++) {
    s16x8 ah = g2f8(&Wo[(size_t)(g0t + lr) * 256 + kk * 32 + lc * 8]);
    s16x8 bh;
#pragma unroll
    for (int j = 0; j < 8; j++)
      bh[j] = (short)f2bf(wv_l[(kk * 32 + lc * 8 + j) * 64 + dl0 + lr]);
    acc = MFMA(ah, bh, acc);
  }
#pragma unroll
  for (int q = 0; q < 4; q++)
    wvo[(g0t + 4 * lc + q) * 128 + d0 + lr] = f2bf(acc[q]);
}

// ---------------- proj_k: Q, K, VWO (XCD-aligned, 256 blocks x 512 thr) ------
__global__ __launch_bounds__(512) void proj_k(
    const float* __restrict__ goals, const float* __restrict__ agents,
    const float* __restrict__ Wq, const float* __restrict__ bq,
    const float* __restrict__ Wk, const float* __restrict__ bk,
    float* __restrict__ ws) {
  unsigned short* qbf  = (unsigned short*)(ws + QBF_OFF);
  unsigned short* kbf  = (unsigned short*)(ws + KBF_OFF);
  unsigned short* vwot = (unsigned short*)(ws + VWOT_OFF);
  const unsigned short* wvo = (const unsigned short*)(ws + WVO_OFF);
  const float* bvo = ws + BVO;

  __shared__ __align__(16) float xg[16 * 68];
  __shared__ __align__(16) float xa[16 * 132];

  int t = threadIdx.x;
  int bid = blockIdx.x;
  int xcd = bid & 7, j = bid >> 3;
  int batch = 2 * xcd + (j & 1);
  int sub = j >> 1;
  int r0 = batch * 128 + (sub >> 1) * 16;
  int colbase = (sub & 1) * 128;

  for (int i = t; i < 1024; i += 512) xg[(i >> 6) * 68 + (i & 63)] = goals[(size_t)r0 * 64 + i];
  for (int i = t; i < 2048; i += 512) xa[(i >> 7) * 132 + (i & 127)] = agents[(size_t)r0 * 128 + i];
  __syncthreads();

  int w = t >> 6, l = t & 63, lr = l & 15, lc = l >> 4;
  int oc = colbase + w * 16 + lr;

  // ---- Q: k=64, hi/lo ----
  {
    f32x4 acc = {0.f, 0.f, 0.f, 0.f};
#pragma unroll
    for (int kk = 0; kk < 2; kk++) {
      s16x8 ahi, alo, bhi, blo;
      split8(&xg[lr * 68 + kk * 32 + lc * 8], &ahi, &alo);
      split8(&Wq[(size_t)oc * 64 + kk * 32 + lc * 8], &bhi, &blo);
      acc = MFMA(ahi, bhi, acc);
      acc = MFMA(alo, bhi, acc);
      acc = MFMA(ahi, blo, acc);
    }
    float bqv = bq[oc];
#pragma unroll
    for (int q = 0; q < 4; q++)
      qbf[(size_t)(r0 + 4 * lc + q) * 256 + oc] = f2bf(acc[q] + bqv);
  }
  // ---- K: k=128, hi/lo ----
  {
    f32x4 acc = {0.f, 0.f, 0.f, 0.f};
#pragma unroll
    for (int kk = 0; kk < 4; kk++) {
      s16x8 ahi, alo, bhi, blo;
      split8(&xa[lr * 132 + kk * 32 + lc * 8], &ahi, &alo);
      split8(&Wk[(size_t)oc * 128 + kk * 32 + lc * 8], &bhi, &blo);
      acc = MFMA(ahi, bhi, acc);
      acc = MFMA(alo, bhi, acc);
      acc = MFMA(ahi, blo, acc);
    }
    float bkv = bk[oc];
#pragma unroll
    for (int q = 0; q < 4; q++)
      kbf[(size_t)(r0 + 4 * lc + q) * 256 + oc] = f2bf(acc[q] + bkv);
  }
  // ---- VWO = agents x Wvo^T + bvo: k=128, single-bf16 out, transposed -------
  {
    f32x4 acc = {0.f, 0.f, 0.f, 0.f};
#pragma unroll
    for (int kk = 0; kk < 4; kk++) {
      s16x8 ahi, alo;
      split8(&xa[lr * 132 + kk * 32 + lc * 8], &ahi, &alo);
      s16x8 bh = *(const s16x8*)(wvo + (size_t)oc * 128 + kk * 32 + lc * 8);
      acc = MFMA(ahi, bh, acc);
      acc = MFMA(alo, bh, acc);
    }
    float bvov = bvo[oc];
    int m0 = r0 & 127;
#pragma unroll
    for (int q = 0; q < 4; q++)
      vwot[(size_t)(batch * 256 + oc) * 128 + m0 + 4 * lc + q] = f2bf(acc[q] + bvov);
  }
}

// ---------------- attn_k: 256 blocks x 1024 thr, phases L,S,PVW,SK ----------
__global__ __launch_bounds__(1024) void attn_k(
    const float* __restrict__ goals, const float* __restrict__ agents_local,
    const float* __restrict__ u1, const float* __restrict__ u2,
    const float* __restrict__ bo, const float* __restrict__ Wsm,
    const float* __restrict__ bs, const float* __restrict__ ws,
    float* __restrict__ out) {
  const unsigned short* Qbf  = (const unsigned short*)(ws + QBF_OFF);
  const unsigned short* Kbf  = (const unsigned short*)(ws + KBF_OFF);
  const unsigned short* VWOT = (const unsigned short*)(ws + VWOT_OFF);
  float* o_logit = out + LOGIT_OFF;
  float* o_mask  = out + MASK_OFF;
  float* o_attn  = out + ATTN_OFF;
  float* o_out   = out + OUT_OFF;

  int bid = blockIdx.x;
  int xcd = bid & 7, idx = bid >> 3;
  int b  = 2 * xcd + (idx & 1);
  int n0 = (idx >> 1) << 3;
  int rtile = n0 & 0x70;
  int soff  = n0 & 8;
  int t = threadIdx.x;
  int w = t >> 6, l = t & 63, lr = l & 15, lc = l >> 4;

  __shared__ __align__(16) float Spp[2][8][132];
  __shared__ __align__(16) unsigned short Wb[16 * 136];
  __shared__ __align__(16) float outb[8 * 260];
  __shared__ float redmax[8][2], redsum[8][2];

  // ---- prefetch: u1/u2 (nontemporal), bo, 4 VWOT B-frags ----
  int pm = t & 127, prl = t >> 7;
  int prow = b * 128 + n0 + prl;
  float uu1 = __builtin_nontemporal_load(&u1[(size_t)prow * 128 + pm]);
  float uu2 = __builtin_nontemporal_load(&u2[(size_t)prow * 128 + pm]);
  int g0 = w * 16;
  float bov = bo[g0 + lr];
  const s16x8* vhp = (const s16x8*)(VWOT + (size_t)(b * 256 + g0 + lr) * 128);
  s16x8 fh0 = vhp[lc], fh1 = vhp[4 + lc], fh2 = vhp[8 + lc], fh3 = vhp[12 + lc];

  // ---- phase L: logits MFMA. wave w: m-tile = w&7, k-half = w>>3 ----
  {
    int mt = w & 7, kh = w >> 3;
    const s16x8* ap = (const s16x8*)(Qbf + (size_t)(b * 128 + rtile + lr) * 256 + kh * 128);
    const s16x8* bp = (const s16x8*)(Kbf + (size_t)(b * 128 + mt * 16 + lr) * 256 + kh * 128);
    f32x4 acc = {0.f, 0.f, 0.f, 0.f};
#pragma unroll
    for (int kk = 0; kk < 4; kk++)
      acc = MFMA(ap[kk * 4 + lc], bp[kk * 4 + lc], acc);
    if ((lc >> 1) == (soff >> 3)) {
#pragma unroll
      for (int q = 0; q < 4; q++) Spp[kh][(4 * lc + q) & 7][mt * 16 + lr] = acc[q];
    }
    if (t < 544) ((unsigned int*)(Wb + (soff ^ 8) * 136))[t] = 0u;
  }
  __syncthreads();

  // ---- phase S: gumbel-sigmoid mask + scores + softmax ----
  {
    int half = (t >> 6) & 1;
    float lg = (Spp[0][prl][pm] + Spp[1][prl][pm]) * 0.0625f;
    float g1 = -__logf(-__logf(uu1 + 1e-20f) + 1e-20f);
    float g2 = -__logf(-__logf(uu2 + 1e-20f) + 1e-20f);
    float mkv = 1.0f / (1.0f + __expf(-(lg + g1 - g2)));   // TAU = 1
    __builtin_nontemporal_store(mkv, &o_mask[(size_t)prow * 128 + pm]);
    float sc = lg + __logf(mkv + 1e-8f);
    float v = sc;
#pragma unroll
    for (int off = 32; off >= 1; off >>= 1) v = fmaxf(v, __shfl_xor(v, off));
    if (l == 0) redmax[prl][half] = v;
    __syncthreads();
    float rmax = fmaxf(redmax[prl][0], redmax[prl][1]);
    float e = __expf(sc - rmax);
    float s = e;
#pragma unroll
    for (int off = 32; off >= 1; off >>= 1) s += __shfl_xor(s, off);
    if (l == 0) redsum[prl][half] = s;
    __syncthreads();
    float rsum = redsum[prl][0] + redsum[prl][1];
    float attn = e / rsum;
    __builtin_nontemporal_store(attn, &o_attn[(size_t)prow * 128 + pm]);
    Wb[(soff + prl) * 136 + pm] = f2bf(attn * mkv);
  }
  __syncthreads();

  // ---- phase PVW: out = Wb x VWO + bo. wave w -> g-tile g0 (4 MFMAs) ----
  {
    s16x8 a0 = *(const s16x8*)(Wb + lr * 136 + 0 * 32 + lc * 8);
    s16x8 a1 = *(const s16x8*)(Wb + lr * 136 + 1 * 32 + lc * 8);
    s16x8 a2 = *(const s16x8*)(Wb + lr * 136 + 2 * 32 + lc * 8);
    s16x8 a3 = *(const s16x8*)(Wb + lr * 136 + 3 * 32 + lc * 8);
    f32x4 acc = {0.f, 0.f, 0.f, 0.f};
    acc = MFMA(a0, fh0, acc);
    acc = MFMA(a1, fh1, acc);
    acc = MFMA(a2, fh2, acc);
    acc = MFMA(a3, fh3, acc);
    if ((lc >> 1) == (soff >> 3)) {
#pragma unroll
      for (int q = 0; q < 4; q++) {
        int rloc = (4 * lc + q) & 7;
        float val = acc[q] + bov;
        __builtin_nontemporal_store(val, &o_out[(size_t)(b * 128 + n0 + rloc) * 256 + g0 + lr]);
        outb[rloc * 260 + g0 + lr] = val;
      }
    }
  }
  __syncthreads();

  // ---- phase SK: skill logits. t = (rloc<<7)|(s<<3)|p, 8-way split-K ----
  {
    int rloc = t >> 7, s = (t >> 3) & 15, p = t & 7;
    int row = b * 128 + n0 + rloc;
    const float4* Ws4 = (const float4*)(Wsm + s * 384);
    const float4* lp4 = (const float4*)(agents_local + (size_t)row * 64);
    const float4* gp4 = (const float4*)(goals + (size_t)row * 64);
    float acc = 0.f;
#pragma unroll
    for (int i = 0; i < 12; i++) {
      int cc = p * 48 + i * 4;
      float4 c4;
      if (cc < 64)       c4 = lp4[cc >> 2];
      else if (cc < 128) c4 = gp4[(cc - 64) >> 2];
      else               c4 = *(const float4*)&outb[rloc * 260 + (cc - 128)];
      float4 w4 = Ws4[cc >> 2];
      acc = fmaf(w4.x, c4.x, fmaf(w4.y, c4.y, fmaf(w4.z, c4.z, fmaf(w4.w, c4.w, acc))));
    }
    acc += __shfl_xor(acc, 1);
    acc += __shfl_xor(acc, 2);
    acc += __shfl_xor(acc, 4);
    if (p == 0) __builtin_nontemporal_store(acc + bs[s], &o_logit[row * 16 + s]);
  }
}

extern "C" void kernel_launch(void* const* d_in, const int* in_sizes, int n_in,
                              void* d_out, int out_size, void* d_ws, size_t ws_size,
                              hipStream_t stream) {
  const float* goals        = (const float*)d_in[0];
  const float* agents       = (const float*)d_in[1];
  const float* agents_local = (const float*)d_in[2];
  const float* u1           = (const float*)d_in[3];
  const float* u2           = (const float*)d_in[4];
  const float* Wq = (const float*)d_in[5];
  const float* bq = (const float*)d_in[6];
  const float* Wk = (const float*)d_in[7];
  const float* bk = (const float*)d_in[8];
  const float* Wv = (const float*)d_in[9];
  const float* bv = (const float*)d_in[10];
  const float* Wo = (const float*)d_in[11];
  const float* bo = (const float*)d_in[12];
  const float* Wsm = (const float*)d_in[13];
  const float* bs  = (const float*)d_in[14];
  float* out = (float*)d_out;
  float* ws  = (float*)d_ws;

  wvo_k<<<32, 256, 0, stream>>>(Wo, Wv, bv, ws);
  proj_k<<<256, 512, 0, stream>>>(goals, agents, Wq, bq, Wk, bk, ws);
  attn_k<<<256, 1024, 0, stream>>>(goals, agents_local, u1, u2, bo, Wsm, bs, ws, out);
}

// Round 16
// 33.829 us; speedup vs baseline: 1.2079x; 1.0362x over previous
//
#include <hip/hip_runtime.h>
#include <math.h>

// Problem constants: B=16, N=128, h=256, goal_dim=64, obs_dim=128, local=64, skills=16
// R16 = R10 (best, 33.9us) + non-temporal streaming (u1/u2 loads, output stores)
// + early register-prefetch of the 4 VT B-fragments. No structural/math change.

typedef float f32x4 __attribute__((ext_vector_type(4)));
typedef short s16x8 __attribute__((ext_vector_type(8)));

// ---- workspace layout (float offsets) ----
#define WOBF_OFF  0        // bf16 [256][256] (row-major, = original Wo layout)
#define QBF_OFF   32768    // bf16 [2048][256] row-major
#define KBF_OFF   294912   // bf16 [2048][256] row-major
#define VTBF_OFF  557056   // bf16 [16][256][128]  (V transposed per batch)

// ---- output layout (float offsets, tuple return order) ----
#define LOGIT_OFF 0        // [16][128][16]
#define MASK_OFF  32768    // [16][128][128]
#define ATTN_OFF  294912   // [16][128][128]
#define OUT_OFF   557056   // [16][128][256]

static __device__ __forceinline__ unsigned short f2bf(float x) {
  unsigned int u = __float_as_uint(x);
  u = (u + 0x7fffu + ((u >> 16) & 1u)) >> 16;   // RNE
  return (unsigned short)u;
}
static __device__ __forceinline__ float bf2f(unsigned short h) {
  return __uint_as_float(((unsigned int)h) << 16);
}

// split 8 consecutive f32 (16B-aligned) into hi/lo bf16 MFMA fragments
static __device__ __forceinline__ void split8(const float* __restrict__ p,
                                              s16x8* hi, s16x8* lo) {
  float4 x0 = *(const float4*)p;
  float4 x1 = *(const float4*)(p + 4);
  float xs[8] = {x0.x, x0.y, x0.z, x0.w, x1.x, x1.y, x1.z, x1.w};
#pragma unroll
  for (int j = 0; j < 8; j++) {
    unsigned short h = f2bf(xs[j]);
    (*hi)[j] = (short)h;
    (*lo)[j] = (short)f2bf(xs[j] - bf2f(h));
  }
}
#define MFMA(a, b, c) __builtin_amdgcn_mfma_f32_16x16x32_bf16((a), (b), (c), 0, 0, 0)

// ---------------- proj_k: R10 verbatim (XCD-aligned mapping) ----------------
__global__ __launch_bounds__(512) void proj_k(
    const float* __restrict__ goals, const float* __restrict__ agents,
    const float* __restrict__ Wq, const float* __restrict__ bq,
    const float* __restrict__ Wk, const float* __restrict__ bk,
    const float* __restrict__ Wv, const float* __restrict__ bv,
    const float* __restrict__ Wo, float* __restrict__ ws) {
  unsigned short* qbf  = (unsigned short*)(ws + QBF_OFF);
  unsigned short* kbf  = (unsigned short*)(ws + KBF_OFF);
  unsigned short* vtbf = (unsigned short*)(ws + VTBF_OFF);
  unsigned short* wobf = (unsigned short*)(ws + WOBF_OFF);

  __shared__ __align__(16) float xg[16 * 68];
  __shared__ __align__(16) float xa[16 * 132];

  int t = threadIdx.x;
  int bid = blockIdx.x;
  int xcd = bid & 7, j = bid >> 3;
  int bb = 2 * xcd + (j & 1);
  int sub = j >> 1;
  int r0 = bb * 128 + (sub >> 1) * 16;
  int colbase = (sub & 1) * 128;

  for (int i = t; i < 1024; i += 512) xg[(i >> 6) * 68 + (i & 63)] = goals[(size_t)r0 * 64 + i];
  for (int i = t; i < 2048; i += 512) xa[(i >> 7) * 132 + (i & 127)] = agents[(size_t)r0 * 128 + i];
  if (t < 256) {
    int jj = bid * 256 + t;
    wobf[jj] = f2bf(Wo[jj]);
  }
  __syncthreads();

  int w = t >> 6, l = t & 63, lr = l & 15, lc = l >> 4;
  int oc = colbase + w * 16 + lr;

  {
    f32x4 acc = {0.f, 0.f, 0.f, 0.f};
#pragma unroll
    for (int kk = 0; kk < 2; kk++) {
      s16x8 ahi, alo, bhi, blo;
      split8(&xg[lr * 68 + kk * 32 + lc * 8], &ahi, &alo);
      split8(&Wq[(size_t)oc * 64 + kk * 32 + lc * 8], &bhi, &blo);
      acc = MFMA(ahi, bhi, acc);
      acc = MFMA(alo, bhi, acc);
      acc = MFMA(ahi, blo, acc);
    }
    float bqv = bq[oc];
#pragma unroll
    for (int q = 0; q < 4; q++)
      qbf[(size_t)(r0 + 4 * lc + q) * 256 + oc] = f2bf(acc[q] + bqv);
  }
  {
    f32x4 acc = {0.f, 0.f, 0.f, 0.f};
#pragma unroll
    for (int kk = 0; kk < 4; kk++) {
      s16x8 ahi, alo, bhi, blo;
      split8(&xa[lr * 132 + kk * 32 + lc * 8], &ahi, &alo);
      split8(&Wk[(size_t)oc * 128 + kk * 32 + lc * 8], &bhi, &blo);
      acc = MFMA(ahi, bhi, acc);
      acc = MFMA(alo, bhi, acc);
      acc = MFMA(ahi, blo, acc);
    }
    float bkv = bk[oc];
#pragma unroll
    for (int q = 0; q < 4; q++)
      kbf[(size_t)(r0 + 4 * lc + q) * 256 + oc] = f2bf(acc[q] + bkv);
  }
  {
    f32x4 acc = {0.f, 0.f, 0.f, 0.f};
#pragma unroll
    for (int kk = 0; kk < 4; kk++) {
      s16x8 ahi, alo, bhi, blo;
      split8(&xa[lr * 132 + kk * 32 + lc * 8], &ahi, &alo);
      split8(&Wv[(size_t)oc * 128 + kk * 32 + lc * 8], &bhi, &blo);
      acc = MFMA(ahi, bhi, acc);
      acc = MFMA(alo, bhi, acc);
      acc = MFMA(ahi, blo, acc);
    }
    float bvv = bv[oc];
    int m0 = r0 & 127;
#pragma unroll
    for (int q = 0; q < 4; q++)
      vtbf[(size_t)(bb * 256 + oc) * 128 + m0 + 4 * lc + q] = f2bf(acc[q] + bvv);
  }
}

// ---------------- attn_k: R10 + NT streams + VT-frag prefetch ----------------
__global__ __launch_bounds__(1024) void attn_k(
    const float* __restrict__ goals, const float* __restrict__ agents_local,
    const float* __restrict__ u1, const float* __restrict__ u2,
    const float* __restrict__ bo, const float* __restrict__ Wsm,
    const float* __restrict__ bs, const float* __restrict__ ws,
    float* __restrict__ out) {
  const unsigned short* Qbf  = (const unsigned short*)(ws + QBF_OFF);
  const unsigned short* Kbf  = (const unsigned short*)(ws + KBF_OFF);
  const unsigned short* VTbf = (const unsigned short*)(ws + VTBF_OFF);
  const unsigned short* Wobf = (const unsigned short*)(ws + WOBF_OFF);
  float* o_logit = out + LOGIT_OFF;
  float* o_mask  = out + MASK_OFF;
  float* o_attn  = out + ATTN_OFF;
  float* o_out   = out + OUT_OFF;

  int bid = blockIdx.x;
  int xcd = bid & 7, idx = bid >> 3;
  int b  = 2 * xcd + (idx & 1);
  int n0 = (idx >> 1) << 3;
  int rtile = n0 & 0x70;
  int soff  = n0 & 8;
  int t = threadIdx.x;
  int w = t >> 6, l = t & 63, lr = l & 15, lc = l >> 4;

  __shared__ __align__(16) float Spp[2][8][132];
  __shared__ __align__(16) unsigned short Wb[16 * 136];
  __shared__ __align__(16) unsigned short Ib[16 * 264];
  __shared__ __align__(16) float outb[8 * 260];
  __shared__ float redmax[8][2], redsum[8][2];

  // ---- prefetch: u1/u2 (NT), bo, 4 VT B-frags (hidden under phases L+S) ----
  int pm = t & 127, prl = t >> 7;
  int prow = b * 128 + n0 + prl;
  float uu1 = __builtin_nontemporal_load(&u1[(size_t)prow * 128 + pm]);
  float uu2 = __builtin_nontemporal_load(&u2[(size_t)prow * 128 + pm]);
  int h0g = w * 16;
  float bov = bo[h0g + lr];
  const s16x8* vtp = (const s16x8*)(VTbf + (size_t)(b * 256 + h0g + lr) * 128);
  s16x8 fv0 = vtp[lc], fv1 = vtp[4 + lc], fv2 = vtp[8 + lc], fv3 = vtp[12 + lc];

  // ---- phase L: logits MFMA. wave w: m-tile = w&7, k-half = w>>3 ----
  {
    int mt = w & 7, kh = w >> 3;
    const s16x8* ap = (const s16x8*)(Qbf + (size_t)(b * 128 + rtile + lr) * 256 + kh * 128);
    const s16x8* bp = (const s16x8*)(Kbf + (size_t)(b * 128 + mt * 16 + lr) * 256 + kh * 128);
    f32x4 acc = {0.f, 0.f, 0.f, 0.f};
#pragma unroll
    for (int kk = 0; kk < 4; kk++)
      acc = MFMA(ap[kk * 4 + lc], bp[kk * 4 + lc], acc);
    if ((lc >> 1) == (soff >> 3)) {
#pragma unroll
      for (int q = 0; q < 4; q++) Spp[kh][(4 * lc + q) & 7][mt * 16 + lr] = acc[q];
    }
    if (t < 544) ((unsigned int*)(Wb + (soff ^ 8) * 136))[t] = 0u;
  }
  __syncthreads();

  // ---- phase S: gumbel-sigmoid mask + scores + softmax ----
  {
    int half = (t >> 6) & 1;
    float lg = (Spp[0][prl][pm] + Spp[1][prl][pm]) * 0.0625f;
    float g1 = -__logf(-__logf(uu1 + 1e-20f) + 1e-20f);
    float g2 = -__logf(-__logf(uu2 + 1e-20f) + 1e-20f);
    float mkv = 1.0f / (1.0f + __expf(-(lg + g1 - g2)));   // TAU = 1
    __builtin_nontemporal_store(mkv, &o_mask[(size_t)prow * 128 + pm]);
    float sc = lg + __logf(mkv + 1e-8f);
    float v = sc;
#pragma unroll
    for (int off = 32; off >= 1; off >>= 1) v = fmaxf(v, __shfl_xor(v, off));
    if (l == 0) redmax[prl][half] = v;
    __syncthreads();
    float rmax = fmaxf(redmax[prl][0], redmax[prl][1]);
    float e = __expf(sc - rmax);
    float s = e;
#pragma unroll
    for (int off = 32; off >= 1; off >>= 1) s += __shfl_xor(s, off);
    if (l == 0) redsum[prl][half] = s;
    __syncthreads();
    float rsum = redsum[prl][0] + redsum[prl][1];
    float attn = e / rsum;
    __builtin_nontemporal_store(attn, &o_attn[(size_t)prow * 128 + pm]);
    Wb[(soff + prl) * 136 + pm] = f2bf(attn * mkv);
  }
  __syncthreads();

  // ---- phase PV: info = W x V. wave w -> h-tile h0g (4 MFMAs, prefetched B) --
  {
    s16x8 a0 = *(const s16x8*)(Wb + lr * 136 + 0 * 32 + lc * 8);
    s16x8 a1 = *(const s16x8*)(Wb + lr * 136 + 1 * 32 + lc * 8);
    s16x8 a2 = *(const s16x8*)(Wb + lr * 136 + 2 * 32 + lc * 8);
    s16x8 a3 = *(const s16x8*)(Wb + lr * 136 + 3 * 32 + lc * 8);
    f32x4 acc = {0.f, 0.f, 0.f, 0.f};
    acc = MFMA(a0, fv0, acc);
    acc = MFMA(a1, fv1, acc);
    acc = MFMA(a2, fv2, acc);
    acc = MFMA(a3, fv3, acc);
#pragma unroll
    for (int q = 0; q < 4; q++) Ib[(4 * lc + q) * 264 + h0g + lr] = f2bf(acc[q]);
  }
  __syncthreads();

  // ---- phase O: out = info x Wo^T. wave w -> g-tile g0 (8 MFMAs) ----
  {
    int g0 = w * 16;
    f32x4 acc = {0.f, 0.f, 0.f, 0.f};
#pragma unroll
    for (int kk = 0; kk < 8; kk++) {
      s16x8 a = *(const s16x8*)(Ib + lr * 264 + kk * 32 + lc * 8);
      s16x8 bfr = *(const s16x8*)(Wobf + (size_t)(g0 + lr) * 256 + kk * 32 + lc * 8);
      acc = MFMA(a, bfr, acc);
    }
    if ((lc >> 1) == (soff >> 3)) {
#pragma unroll
      for (int q = 0; q < 4; q++) {
        int rloc = (4 * lc + q) & 7;
        float val = acc[q] + bov;
        __builtin_nontemporal_store(val, &o_out[(size_t)(b * 128 + n0 + rloc) * 256 + g0 + lr]);
        outb[rloc * 260 + g0 + lr] = val;
      }
    }
  }
  __syncthreads();

  // ---- phase K: skill logits. t = (rloc<<7)|(s<<3)|p, 8-way split-K ----
  {
    int rloc = t >> 7, s = (t >> 3) & 15, p = t & 7;
    int row = b * 128 + n0 + rloc;
    const float4* Ws4 = (const float4*)(Wsm + s * 384);
    const float4* lp4 = (const float4*)(agents_local + (size_t)row * 64);
    const float4* gp4 = (const float4*)(goals + (size_t)row * 64);
    float acc = 0.f;
#pragma unroll
    for (int i = 0; i < 12; i++) {
      int cc = p * 48 + i * 4;
      float4 c4;
      if (cc < 64)       c4 = lp4[cc >> 2];
      else if (cc < 128) c4 = gp4[(cc - 64) >> 2];
      else               c4 = *(const float4*)&outb[rloc * 260 + (cc - 128)];
      float4 w4 = Ws4[cc >> 2];
      acc = fmaf(w4.x, c4.x, fmaf(w4.y, c4.y, fmaf(w4.z, c4.z, fmaf(w4.w, c4.w, acc))));
    }
    acc += __shfl_xor(acc, 1);
    acc += __shfl_xor(acc, 2);
    acc += __shfl_xor(acc, 4);
    if (p == 0) __builtin_nontemporal_store(acc + bs[s], &o_logit[row * 16 + s]);
  }
}

extern "C" void kernel_launch(void* const* d_in, const int* in_sizes, int n_in,
                              void* d_out, int out_size, void* d_ws, size_t ws_size,
                              hipStream_t stream) {
  const float* goals        = (const float*)d_in[0];
  const float* agents       = (const float*)d_in[1];
  const float* agents_local = (const float*)d_in[2];
  const float* u1           = (const float*)d_in[3];
  const float* u2           = (const float*)d_in[4];
  const float* Wq = (const float*)d_in[5];
  const float* bq = (const float*)d_in[6];
  const float* Wk = (const float*)d_in[7];
  const float* bk = (const float*)d_in[8];
  const float* Wv = (const float*)d_in[9];
  const float* bv = (const float*)d_in[10];
  const float* Wo = (const float*)d_in[11];
  const float* bo = (const float*)d_in[12];
  const float* Wsm = (const float*)d_in[13];
  const float* bs  = (const float*)d_in[14];
  float* out = (float*)d_out;
  float* ws  = (float*)d_ws;

  proj_k<<<256, 512, 0, stream>>>(goals, agents, Wq, bq, Wk, bk, Wv, bv, Wo, ws);
  attn_k<<<256, 1024, 0, stream>>>(goals, agents_local, u1, u2, bo, Wsm, bs, ws, out);
}